// Round 16
// baseline (249.072 us; speedup 1.0000x reference)
//
#include <hip/hip_runtime.h>
#include <hip/hip_bf16.h>

#define NN 20000
#define NE 200000

typedef __bf16 bf16x8 __attribute__((ext_vector_type(8)));
typedef float f32x4 __attribute__((ext_vector_type(4)));
typedef unsigned short u16x8 __attribute__((ext_vector_type(8)));

// ---- workspace layout (bytes) ----
constexpr int TAB_MSG_SCALE = 0;      // f32 element offsets within tabs
constexpr int TAB_MSG_BETA  = 256;
constexpr int TAB_UPD_SCALE = 512;
constexpr int TAB_UPD_BETA  = 768;
constexpr int TAB_TASKC     = 1024;   // task @ att_W1[768:1024] + att_b1
constexpr int TAB_ECM       = 1280;   // 16*512: per 4-dim group g: [ec[4g..] | em[4g..]]
constexpr size_t OFF_WPRET = 40960;    // u16[768*256] n-major
constexpr size_t OFF_W1T   = 434176;   // u16[256*512]
constexpr size_t OFF_W2T   = 696320;   // u16[256*256]
constexpr size_t OFF_CNT   = 827392;   // i32[NN]
constexpr size_t OFF_PTRS  = 907392;   // i32[NN+1]
constexpr size_t OFF_PWORK = 987648;   // i32[NN]
constexpr size_t OFF_SRCET = 1067648;  // u32[NE]  src | et<<16 (CSR order)
constexpr size_t OFF_UPDB  = 1867648;  // u16[NN*256]  aggregated+modulated upd half (bf16)
constexpr size_t OFF_G     = 12107648; // u16[NN*512]  [P1 row(256) | M row(256)] per node
constexpr size_t OFF_P2B   = 32587648; // u16[NN*256]  P2 + taskc (bf16)
constexpr size_t WS_NEED   = 42827648;

constexpr int ROW_BLOCKS = (NN + 63)/64;   // 313 row-blocks; x4 n-chunks; +1 scan

__device__ __forceinline__ float bf2f(unsigned short u){
  union { unsigned int i; float f; } v; v.i = ((unsigned int)u) << 16; return v.f;
}
__device__ __forceinline__ unsigned short f2bf(float f){
  __bf16 h = (__bf16)f; unsigned short u; __builtin_memcpy(&u, &h, 2); return u;
}
__device__ __forceinline__ float gelu_f(float x){
  return 0.5f * x * (1.0f + erff(x * 0.70710678118654752f));
}
// fast sigmoid-gelu: max abs err ~0.01 vs exact
__device__ __forceinline__ float gelu_fast(float x){
  return x / (1.0f + __expf(-1.702f * x));
}
// overflow-safe fast tanh
__device__ __forceinline__ float tanh_fast(float x){
  float e = __expf(2.0f * x);
  return 1.0f - 2.0f / (e + 1.0f);
}
__device__ __forceinline__ float sum16(const float* p){
  float a = ((p[0]+p[1])+(p[2]+p[3])) + ((p[4]+p[5])+(p[6]+p[7]));
  float b = ((p[8]+p[9])+(p[10]+p[11])) + ((p[12]+p[13])+(p[14]+p[15]));
  return a + b;
}

// ---------------- K_setup: fused tables + weight transposes + degree histogram ----------------
// blocks [0,35): tables; [35,1315): prep; [1315,2097): hist. All independent.
__global__ __launch_bounds__(256) void k_setup(
    const float* __restrict__ task, const float* __restrict__ eemb,
    const float* __restrict__ msg_W, const float* __restrict__ msg_b,
    const float* __restrict__ att_W1, const float* __restrict__ att_b1,
    const float* __restrict__ ma_W1, const float* __restrict__ ma_b1,
    const float* __restrict__ ma_W2, const float* __restrict__ ma_b2,
    const float* __restrict__ ua_W1, const float* __restrict__ ua_b1,
    const float* __restrict__ ua_W2, const float* __restrict__ ua_b2,
    const float* __restrict__ up_W1, const float* __restrict__ up_W2,
    const int* __restrict__ eidx,
    float* __restrict__ tabs,
    unsigned short* __restrict__ WpreT, unsigned short* __restrict__ W1T,
    unsigned short* __restrict__ W2T, int* __restrict__ cnt)
{
  __shared__ float s_in[512];
  __shared__ float s_h[512];
  int bb = blockIdx.x, tid = threadIdx.x;
  if (bb >= 1315){
    int e = (bb - 1315)*256 + tid;
    if (e < NE) atomicAdd(&cnt[eidx[NE + e]], 1);
    return;
  }
  if (bb >= 35){
    int b = bb - 35;
    if (b < 768){
      int n = b;
      float v;
      if (n < 256)      v = msg_W[tid*256 + n];
      else if (n < 512) v = att_W1[tid*256 + (n - 256)];
      else              v = att_W1[(256 + tid)*256 + (n - 512)];
      WpreT[n*256 + tid] = f2bf(v);
    } else if (b < 1024){
      int n = b - 768;
      W1T[n*512 + tid]       = f2bf(up_W1[tid*256 + n]);
      W1T[n*512 + 256 + tid] = f2bf(up_W1[(256 + tid)*256 + n]);
    } else {
      int n = b - 1024;
      W2T[n*256 + tid] = f2bf(up_W2[tid*256 + n]);
    }
    return;
  }
  int b = bb;
  if (b < 2){
    const float* W1 = b ? ua_W1 : ma_W1;  const float* b1 = b ? ua_b1 : ma_b1;
    const float* W2 = b ? ua_W2 : ma_W2;  const float* b2 = b ? ua_b2 : ma_b2;
    s_in[tid] = task[tid];
    __syncthreads();
    #pragma unroll
    for (int jj = 0; jj < 2; ++jj){
      int j = tid + jj*256;
      float pacc[16];
      #pragma unroll
      for (int u = 0; u < 16; ++u) pacc[u] = 0.f;
      for (int k0 = 0; k0 < 256; k0 += 16){
        float wv[16];
        #pragma unroll
        for (int u = 0; u < 16; ++u) wv[u] = W1[(k0 + u)*512 + j];
        #pragma unroll
        for (int u = 0; u < 16; ++u) pacc[u] += s_in[k0 + u] * wv[u];
      }
      s_h[j] = gelu_f(b1[j] + sum16(pacc));
    }
    __syncthreads();
    float o[2];
    #pragma unroll
    for (int jj = 0; jj < 2; ++jj){
      int j = tid + jj*256;
      float pacc[16];
      #pragma unroll
      for (int u = 0; u < 16; ++u) pacc[u] = 0.f;
      for (int k0 = 0; k0 < 512; k0 += 16){
        float wv[16];
        #pragma unroll
        for (int u = 0; u < 16; ++u) wv[u] = W2[(k0 + u)*512 + j];
        #pragma unroll
        for (int u = 0; u < 16; ++u) pacc[u] += s_h[k0 + u] * wv[u];
      }
      o[jj] = b2[j] + sum16(pacc);
    }
    float* scale = tabs + (b ? TAB_UPD_SCALE : TAB_MSG_SCALE);
    float* beta  = tabs + (b ? TAB_UPD_BETA  : TAB_MSG_BETA);
    scale[tid] = 1.0f + 0.5f * tanhf(o[0]);
    beta[tid]  = o[1];
  } else if (b == 2){
    s_in[tid] = task[tid];
    __syncthreads();
    float pacc[16];
    #pragma unroll
    for (int u = 0; u < 16; ++u) pacc[u] = 0.f;
    for (int k0 = 0; k0 < 256; k0 += 16){
      float wv[16];
      #pragma unroll
      for (int u = 0; u < 16; ++u) wv[u] = att_W1[(768 + k0 + u)*256 + tid];
      #pragma unroll
      for (int u = 0; u < 16; ++u) pacc[u] += s_in[k0 + u] * wv[u];
    }
    tabs[TAB_TASKC + tid] = att_b1[tid] + sum16(pacc);
  } else if (b < 19){
    // EM (message table): ECM group-interleaved, +4 half
    int t = b - 3;
    s_in[tid] = eemb[t*256 + tid];
    __syncthreads();
    float pacc[16];
    #pragma unroll
    for (int u = 0; u < 16; ++u) pacc[u] = 0.f;
    for (int k0 = 0; k0 < 256; k0 += 16){
      float wv[16];
      #pragma unroll
      for (int u = 0; u < 16; ++u) wv[u] = msg_W[(k0 + u)*256 + tid];
      #pragma unroll
      for (int u = 0; u < 16; ++u) pacc[u] += s_in[k0 + u] * wv[u];
    }
    tabs[TAB_ECM + t*512 + ((tid >> 2) << 3) + 4 + (tid & 3)] = msg_b[tid] + sum16(pacc);
  } else {
    // EC (attention table): ECM group-interleaved, base half
    int t = b - 19;
    s_in[tid] = eemb[t*256 + tid];
    __syncthreads();
    float pacc[16];
    #pragma unroll
    for (int u = 0; u < 16; ++u) pacc[u] = 0.f;
    for (int k0 = 0; k0 < 256; k0 += 16){
      float wv[16];
      #pragma unroll
      for (int u = 0; u < 16; ++u) wv[u] = att_W1[(512 + k0 + u)*256 + tid];
      #pragma unroll
      for (int u = 0; u < 16; ++u) pacc[u] += s_in[k0 + u] * wv[u];
    }
    tabs[TAB_ECM + t*512 + ((tid >> 2) << 3) + (tid & 3)] = sum16(pacc);
  }
}

// ---------------- K1: LDS-staged B, 2D grid (313 row-blocks x 4 n-chunks) + scan ----------------
// block bb<1252: rb=bb>>2 (64 rows), chunk=bb&3 (12 n-tiles). Disjoint outputs.
// block 1252: exclusive prefix sum of cnt -> ptrs/pwork.
__global__ __launch_bounds__(256) void k_gemm_pre(
    const float* __restrict__ X, const unsigned short* __restrict__ WpreT,
    const float* __restrict__ tabs,
    unsigned short* __restrict__ G, unsigned short* __restrict__ P2b,
    const int* __restrict__ cnt, int* __restrict__ ptrs, int* __restrict__ pwork)
{
  __shared__ __align__(16) unsigned short s_b[16*256]; // 8KB, swizzled elem ^= (n&7)<<3
  int tid = threadIdx.x;
  int bb = blockIdx.x;
  if (bb == ROW_BLOCKS*4){
    int* s = (int*)s_b;
    constexpr int PER = (NN + 255)/256;  // 79
    int i0 = tid*PER;
    int tot = 0;
    for (int j = 0; j < PER; ++j){
      int i = i0 + j;
      if (i < NN) tot += cnt[i];
    }
    s[tid] = tot;
    __syncthreads();
    #pragma unroll
    for (int off = 1; off < 256; off <<= 1){
      int t = (tid >= off) ? s[tid - off] : 0;
      __syncthreads();
      s[tid] += t;
      __syncthreads();
    }
    int run = s[tid] - tot;
    for (int j = 0; j < PER; ++j){
      int i = i0 + j;
      if (i < NN){
        ptrs[i]  = run;
        pwork[i] = run;
        run += cnt[i];
      }
    }
    if (tid == 255) ptrs[NN] = s[255];
    return;
  }
  int rb = bb >> 2, chunk = bb & 3;
  int wv = tid >> 6, lane = tid & 63;
  int m0 = rb*64 + wv*16;
  bool valid = (m0 < NN);
  int lo = lane & 15, hi = lane >> 4;
  bf16x8 a[8];
  if (valid){
    const float* xrow = X + (size_t)(m0 + lo)*256 + hi*8;
    #pragma unroll
    for (int kc = 0; kc < 8; ++kc){
      float4 f0 = *(const float4*)(xrow + kc*32);
      float4 f1 = *(const float4*)(xrow + kc*32 + 4);
      bf16x8 v;
      v[0]=(__bf16)f0.x; v[1]=(__bf16)f0.y; v[2]=(__bf16)f0.z; v[3]=(__bf16)f0.w;
      v[4]=(__bf16)f1.x; v[5]=(__bf16)f1.y; v[6]=(__bf16)f1.z; v[7]=(__bf16)f1.w;
      a[kc] = v;
    }
  }
  int sn = tid >> 4, sk0 = (tid & 15)*16;
  int sswz = (sn & 7) << 3;
  int rswz = (lo & 7) << 3;
  for (int t = 0; t < 12; ++t){
    int nt = chunk*12 + t;
    __syncthreads();
    {
      const unsigned short* gsrc = WpreT + (size_t)(nt*16 + sn)*256 + sk0;
      uint4 d0 = *(const uint4*)(gsrc);
      uint4 d1 = *(const uint4*)(gsrc + 8);
      *(uint4*)(s_b + sn*256 + (sk0 ^ sswz))       = d0;
      *(uint4*)(s_b + sn*256 + ((sk0 + 8) ^ sswz)) = d1;
    }
    __syncthreads();
    if (!valid) continue;
    f32x4 acc = {0.f, 0.f, 0.f, 0.f};
    #pragma unroll
    for (int kc = 0; kc < 8; ++kc){
      bf16x8 bfrag = *(const bf16x8*)(s_b + lo*256 + ((kc*32 + hi*8) ^ rswz));
      acc = __builtin_amdgcn_mfma_f32_16x16x32_bf16(a[kc], bfrag, acc, 0, 0, 0);
    }
    int n0 = nt*16;
    if (nt < 16){
      int j = n0 + lo;
      unsigned short* grow = G + (size_t)(m0 + hi*4)*512 + 256 + j;
      #pragma unroll
      for (int r = 0; r < 4; ++r) grow[(size_t)r*512] = f2bf(acc[r]);
    } else if (nt < 32){
      int j = n0 - 256 + lo;
      unsigned short* grow = G + (size_t)(m0 + hi*4)*512 + j;
      #pragma unroll
      for (int r = 0; r < 4; ++r) grow[(size_t)r*512] = f2bf(acc[r]);
    } else {
      int j = n0 - 512 + lo;
      float tcadd = tabs[TAB_TASKC + j];
      unsigned short* prow = P2b + (size_t)(m0 + hi*4)*256 + j;
      #pragma unroll
      for (int r = 0; r < 4; ++r) prow[(size_t)r*256] = f2bf(acc[r] + tcadd);
    }
  }
}

// ---------------- K2c: CSR build ----------------
__global__ __launch_bounds__(256) void k_csr_build(
    const int* __restrict__ eidx, const int* __restrict__ etype,
    int* __restrict__ pwork, unsigned int* __restrict__ srcet)
{
  int e = blockIdx.x*256 + threadIdx.x;
  if (e < NE){
    int dst = eidx[NE + e];
    int pos = atomicAdd(&pwork[dst], 1);
    srcet[pos] = (unsigned int)eidx[e] | ((unsigned int)etype[e] << 16);
  }
}

// ---------------- K3: 2 nodes/wave (proven round-15 structure; 32-bit G offsets) ----------------
__global__ __launch_bounds__(256) void k_agg(
    const int* __restrict__ ptrs, const unsigned int* __restrict__ srcet,
    const unsigned short* __restrict__ G, const unsigned short* __restrict__ P2b,
    const float* __restrict__ tabs, const float* __restrict__ attW2,
    const float* __restrict__ attb2, const float* __restrict__ escale,
    unsigned short* __restrict__ updB)
{
  int wv = threadIdx.x >> 6, lane = threadIdx.x & 63;
  int h = lane >> 5, l = lane & 31;
  int node = blockIdx.x*8 + wv*2 + h;     // grid 2500*8 = NN exactly
  int d0 = l*8;
  float sc = escale[0], bb = attb2[0];

  float q[8], w2v[8];
  {
    u16x8 p2 = *(const u16x8*)(P2b + (size_t)node*256 + d0);
    #pragma unroll
    for (int j = 0; j < 8; ++j) q[j] = bf2f(p2[j]);
    float4 wa = *(const float4*)(attW2 + d0);
    float4 wb = *(const float4*)(attW2 + d0 + 4);
    w2v[0]=wa.x; w2v[1]=wa.y; w2v[2]=wa.z; w2v[3]=wa.w;
    w2v[4]=wb.x; w2v[5]=wb.y; w2v[6]=wb.z; w2v[7]=wb.w;
  }
  const float* ecm_base = tabs + TAB_ECM + (l << 4);   // lane covers groups 2l,2l+1

  int start = ptrs[node], end = ptrs[node + 1];
  float acc[8];
  #pragma unroll
  for (int j = 0; j < 8; ++j) acc[j] = 0.f;
  float W = 0.f;

  unsigned int se0 = 0, se1 = 0;
  u16x8 p1a = {0,0,0,0,0,0,0,0}, mma = {0,0,0,0,0,0,0,0};
  if (start < end){
    se0 = srcet[start];
    const unsigned short* gr = G + (((unsigned)(se0 & 0xFFFFu)) << 9);
    p1a = *(const u16x8*)(gr + d0);
    mma = *(const u16x8*)(gr + 256 + d0);
    if (start + 1 < end) se1 = srcet[start + 1];
  }
  for (int i = start; i < end; ++i){
    u16x8 p1b = p1a, mmb = mma;
    unsigned int se2 = 0;
    if (i + 1 < end){
      const unsigned short* gr = G + (((unsigned)(se1 & 0xFFFFu)) << 9);
      p1b = *(const u16x8*)(gr + d0);
      mmb = *(const u16x8*)(gr + 256 + d0);
    }
    if (i + 2 < end) se2 = srcet[i + 2];
    int et = (int)(se0 >> 16);
    const float* ecm = ecm_base + (et << 9);
    float4 ec0 = *(const float4*)(ecm);
    float4 em0 = *(const float4*)(ecm + 4);
    float4 ec1 = *(const float4*)(ecm + 8);
    float4 em1 = *(const float4*)(ecm + 12);
    float part =
        gelu_fast(bf2f(p1a[0]) + q[0] + ec0.x)*w2v[0]
      + gelu_fast(bf2f(p1a[1]) + q[1] + ec0.y)*w2v[1]
      + gelu_fast(bf2f(p1a[2]) + q[2] + ec0.z)*w2v[2]
      + gelu_fast(bf2f(p1a[3]) + q[3] + ec0.w)*w2v[3]
      + gelu_fast(bf2f(p1a[4]) + q[4] + ec1.x)*w2v[4]
      + gelu_fast(bf2f(p1a[5]) + q[5] + ec1.y)*w2v[5]
      + gelu_fast(bf2f(p1a[6]) + q[6] + ec1.z)*w2v[6]
      + gelu_fast(bf2f(p1a[7]) + q[7] + ec1.w)*w2v[7];
    // reduce within 32-lane half (offsets < 32 never cross the h split)
    part += __shfl_xor(part, 1);
    part += __shfl_xor(part, 2);
    part += __shfl_xor(part, 4);
    part += __shfl_xor(part, 8);
    part += __shfl_xor(part, 16);
    float w = 1.0f + sc*tanh_fast(part + bb);
    acc[0] += w*(bf2f(mma[0]) + em0.x);
    acc[1] += w*(bf2f(mma[1]) + em0.y);
    acc[2] += w*(bf2f(mma[2]) + em0.z);
    acc[3] += w*(bf2f(mma[3]) + em0.w);
    acc[4] += w*(bf2f(mma[4]) + em1.x);
    acc[5] += w*(bf2f(mma[5]) + em1.y);
    acc[6] += w*(bf2f(mma[6]) + em1.z);
    acc[7] += w*(bf2f(mma[7]) + em1.w);
    W += w;
    se0 = se1; se1 = se2; p1a = p1b; mma = mmb;
  }

  float d = fmaxf(W, 1.0f), rd = 1.0f / d;
  unsigned short st[8];
  #pragma unroll
  for (int c = 0; c < 2; ++c){
    float4 ms = *(const float4*)(tabs + TAB_MSG_SCALE + d0 + c*4);
    float4 mb = *(const float4*)(tabs + TAB_MSG_BETA  + d0 + c*4);
    float4 us = *(const float4*)(tabs + TAB_UPD_SCALE + d0 + c*4);
    float4 ub = *(const float4*)(tabs + TAB_UPD_BETA  + d0 + c*4);
    st[c*4+0] = f2bf((ms.x*acc[c*4+0] + mb.x*W)*rd*us.x + ub.x);
    st[c*4+1] = f2bf((ms.y*acc[c*4+1] + mb.y*W)*rd*us.y + ub.y);
    st[c*4+2] = f2bf((ms.z*acc[c*4+2] + mb.z*W)*rd*us.z + ub.z);
    st[c*4+3] = f2bf((ms.w*acc[c*4+3] + mb.w*W)*rd*us.w + ub.w);
  }
  *(u16x8*)(updB + (size_t)node*256 + d0) = *(u16x8*)(st);
}

// ---------------- K4: 32-row dense MLP + residual + in-register LayerNorm (proven) ----------------
__device__ __forceinline__ bf16x8 ldA(const float* xrow, const unsigned short* urow, int ke){
  if (ke < 256){
    float4 f0 = *(const float4*)(xrow + ke);
    float4 f1 = *(const float4*)(xrow + ke + 4);
    bf16x8 v;
    v[0]=(__bf16)f0.x; v[1]=(__bf16)f0.y; v[2]=(__bf16)f0.z; v[3]=(__bf16)f0.w;
    v[4]=(__bf16)f1.x; v[5]=(__bf16)f1.y; v[6]=(__bf16)f1.z; v[7]=(__bf16)f1.w;
    return v;
  }
  return *(const bf16x8*)(urow + (ke - 256));
}

__global__ __launch_bounds__(256) void k_mlp(
    const float* __restrict__ X, const unsigned short* __restrict__ updB,
    const unsigned short* __restrict__ W1T, const unsigned short* __restrict__ W2T,
    const float* __restrict__ up_b1, const float* __restrict__ up_b2,
    const float* __restrict__ ln_g, const float* __restrict__ ln_b,
    float* __restrict__ out)
{
  __shared__ __align__(16) unsigned short s_H[32*256]; // bf16, ^=(row&7)<<3
  __shared__ float s_sum[4*32], s_sq[4*32];
  __shared__ float s_mu[32], s_rs[32];
  int m0 = blockIdx.x*32;
  int tid = threadIdx.x;
  int wv = tid >> 6, lane = tid & 63, lo = lane & 15, hi = lane >> 4;

  const float* x0 = X + (size_t)(m0 + lo)*256;
  const float* x1 = x0 + 16*256;
  const unsigned short* u0 = updB + (size_t)(m0 + lo)*256;
  const unsigned short* u1 = u0 + 16*256;

  f32x4 acc0[4], acc1[4];
  #pragma unroll
  for (int t = 0; t < 4; ++t){
    float b = up_b1[wv*64 + t*16 + lo];
    acc0[t] = (f32x4){b, b, b, b};
    acc1[t] = acc0[t];
  }
  #pragma unroll
  for (int kc = 0; kc < 16; ++kc){
    int ke = kc*32 + hi*8;
    bf16x8 a0 = ldA(x0, u0, ke);
    bf16x8 a1 = ldA(x1, u1, ke);
    #pragma unroll
    for (int t = 0; t < 4; ++t){
      int n = wv*64 + t*16 + lo;
      bf16x8 bf = *(const bf16x8*)(W1T + (size_t)n*512 + ke);
      acc0[t] = __builtin_amdgcn_mfma_f32_16x16x32_bf16(a0, bf, acc0[t], 0, 0, 0);
      acc1[t] = __builtin_amdgcn_mfma_f32_16x16x32_bf16(a1, bf, acc1[t], 0, 0, 0);
    }
  }
  #pragma unroll
  for (int t = 0; t < 4; ++t){
    #pragma unroll
    for (int r = 0; r < 4; ++r){
      int row0 = hi*4 + r, n = wv*64 + t*16 + lo;
      s_H[(row0 << 8) | (n ^ ((row0 & 7) << 3))] = f2bf(gelu_fast(acc0[t][r]));
      int row1 = row0 + 16;
      s_H[(row1 << 8) | (n ^ ((row1 & 7) << 3))] = f2bf(gelu_fast(acc1[t][r]));
    }
  }
  __syncthreads();

  f32x4 y0[4], y1[4];
  #pragma unroll
  for (int t = 0; t < 4; ++t){
    float b = up_b2[wv*64 + t*16 + lo];
    y0[t] = (f32x4){b, b, b, b};
    y1[t] = y0[t];
  }
  #pragma unroll
  for (int kc = 0; kc < 8; ++kc){
    int ke = kc*32 + hi*8;
    bf16x8 af0 = *(const bf16x8*)(s_H + ((lo << 8) | (ke ^ ((lo & 7) << 3))));
    int r1 = lo + 16;
    bf16x8 af1 = *(const bf16x8*)(s_H + ((r1 << 8) | (ke ^ ((r1 & 7) << 3))));
    #pragma unroll
    for (int t = 0; t < 4; ++t){
      int n = wv*64 + t*16 + lo;
      bf16x8 bf = *(const bf16x8*)(W2T + (size_t)n*256 + ke);
      y0[t] = __builtin_amdgcn_mfma_f32_16x16x32_bf16(af0, bf, y0[t], 0, 0, 0);
      y1[t] = __builtin_amdgcn_mfma_f32_16x16x32_bf16(af1, bf, y1[t], 0, 0, 0);
    }
  }

  #pragma unroll
  for (int t = 0; t < 4; ++t){
    #pragma unroll
    for (int r = 0; r < 4; ++r){
      int row0 = hi*4 + r, n = wv*64 + t*16 + lo;
      y0[t][r] += X[(size_t)(m0 + row0)*256 + n];
      y1[t][r] += X[(size_t)(m0 + row0 + 16)*256 + n];
    }
  }

  float ps[2][4], pq[2][4];
  #pragma unroll
  for (int r = 0; r < 4; ++r){
    float s0 = 0.f, q0 = 0.f, s1 = 0.f, q1 = 0.f;
    #pragma unroll
    for (int t = 0; t < 4; ++t){
      s0 += y0[t][r]; q0 += y0[t][r]*y0[t][r];
      s1 += y1[t][r]; q1 += y1[t][r]*y1[t][r];
    }
    #pragma unroll
    for (int off = 1; off < 16; off <<= 1){
      s0 += __shfl_xor(s0, off); q0 += __shfl_xor(q0, off);
      s1 += __shfl_xor(s1, off); q1 += __shfl_xor(q1, off);
    }
    ps[0][r] = s0; pq[0][r] = q0;
    ps[1][r] = s1; pq[1][r] = q1;
  }
  if (lo == 0){
    #pragma unroll
    for (int m = 0; m < 2; ++m){
      #pragma unroll
      for (int r = 0; r < 4; ++r){
        int row = m*16 + hi*4 + r;
        s_sum[wv*32 + row] = ps[m][r];
        s_sq [wv*32 + row] = pq[m][r];
      }
    }
  }
  __syncthreads();
  if (tid < 32){
    float sum = s_sum[tid] + s_sum[32 + tid] + s_sum[64 + tid] + s_sum[96 + tid];
    float sq  = s_sq[tid]  + s_sq[32 + tid]  + s_sq[64 + tid]  + s_sq[96 + tid];
    float mu = sum * (1.0f/256.0f);
    float var = sq * (1.0f/256.0f) - mu*mu;
    s_mu[tid] = mu;
    s_rs[tid] = rsqrtf(var + 1e-5f);
  }
  __syncthreads();

  #pragma unroll
  for (int t = 0; t < 4; ++t){
    int n = wv*64 + t*16 + lo;
    float lg = ln_g[n], lb = ln_b[n];
    #pragma unroll
    for (int r = 0; r < 4; ++r){
      int row0 = hi*4 + r, row1 = row0 + 16;
      out[(size_t)(m0 + row0)*256 + n] = (y0[t][r] - s_mu[row0]) * s_rs[row0] * lg + lb;
      out[(size_t)(m0 + row1)*256 + n] = (y1[t][r] - s_mu[row1]) * s_rs[row1] * lg + lb;
    }
  }
}

extern "C" void kernel_launch(void* const* d_in, const int* in_sizes, int n_in,
                              void* d_out, int out_size, void* d_ws, size_t ws_size,
                              hipStream_t stream)
{
  (void)in_sizes; (void)n_in; (void)out_size;
  if (ws_size < WS_NEED) return;
  const float* X      = (const float*)d_in[0];
  const int*   eidx   = (const int*)d_in[1];
  const int*   etype  = (const int*)d_in[2];
  const float* task   = (const float*)d_in[3];
  const float* eemb   = (const float*)d_in[4];
  const float* msg_W  = (const float*)d_in[5];
  const float* msg_b  = (const float*)d_in[6];
  const float* att_W1 = (const float*)d_in[7];
  const float* att_b1 = (const float*)d_in[8];
  const float* att_W2 = (const float*)d_in[9];
  const float* att_b2 = (const float*)d_in[10];
  const float* escale = (const float*)d_in[11];
  const float* ma_W1  = (const float*)d_in[12];
  const float* ma_b1  = (const float*)d_in[13];
  const float* ma_W2  = (const float*)d_in[14];
  const float* ma_b2  = (const float*)d_in[15];
  const float* up_W1  = (const float*)d_in[16];
  const float* up_b1  = (const float*)d_in[17];
  const float* up_W2  = (const float*)d_in[18];
  const float* up_b2  = (const float*)d_in[19];
  const float* ua_W1  = (const float*)d_in[20];
  const float* ua_b1  = (const float*)d_in[21];
  const float* ua_W2  = (const float*)d_in[22];
  const float* ua_b2  = (const float*)d_in[23];
  const float* ln_g   = (const float*)d_in[24];
  const float* ln_b   = (const float*)d_in[25];
  char* ws = (char*)d_ws;
  float* tabs = (float*)ws;
  unsigned short* WpreT = (unsigned short*)(ws + OFF_WPRET);
  unsigned short* W1T   = (unsigned short*)(ws + OFF_W1T);
  unsigned short* W2T   = (unsigned short*)(ws + OFF_W2T);
  int*          cnt   = (int*)(ws + OFF_CNT);
  int*          ptrs  = (int*)(ws + OFF_PTRS);
  int*          pwork = (int*)(ws + OFF_PWORK);
  unsigned int* srcet = (unsigned int*)(ws + OFF_SRCET);
  unsigned short* updB = (unsigned short*)(ws + OFF_UPDB);
  unsigned short* G    = (unsigned short*)(ws + OFF_G);
  unsigned short* P2b  = (unsigned short*)(ws + OFF_P2B);
  float* out = (float*)d_out;

  hipMemsetAsync(cnt, 0, (size_t)NN*4, stream);
  k_setup<<<2097, 256, 0, stream>>>(task, eemb, msg_W, msg_b, att_W1, att_b1,
                                    ma_W1, ma_b1, ma_W2, ma_b2,
                                    ua_W1, ua_b1, ua_W2, ua_b2,
                                    up_W1, up_W2, eidx,
                                    tabs, WpreT, W1T, W2T, cnt);
  k_gemm_pre<<<ROW_BLOCKS*4 + 1, 256, 0, stream>>>(X, WpreT, tabs, G, P2b,
                                                   cnt, ptrs, pwork);
  k_csr_build<<<(NE + 255)/256, 256, 0, stream>>>(eidx, etype, pwork, srcet);
  k_agg<<<NN/8, 256, 0, stream>>>(ptrs, srcet, G, P2b, tabs,
                                  att_W2, att_b2, escale, updB);
  k_mlp<<<NN/32, 256, 0, stream>>>(X, updB, W1T, W2T, up_b1, up_b2,
                                   ln_g, ln_b, out);
}

// Round 17
// 193.942 us; speedup vs baseline: 1.2843x; 1.2843x over previous
//
#include <hip/hip_runtime.h>
#include <hip/hip_bf16.h>

#define NN 20000
#define NE 200000

typedef __bf16 bf16x8 __attribute__((ext_vector_type(8)));
typedef float f32x4 __attribute__((ext_vector_type(4)));
typedef unsigned short u16x8 __attribute__((ext_vector_type(8)));

// ---- workspace layout (bytes) ----
constexpr int TAB_MSG_SCALE = 0;      // f32 element offsets within tabs
constexpr int TAB_MSG_BETA  = 256;
constexpr int TAB_UPD_SCALE = 512;
constexpr int TAB_UPD_BETA  = 768;
constexpr int TAB_TASKC     = 1024;   // task @ att_W1[768:1024] + att_b1
constexpr int TAB_ECM       = 1280;   // 16*512: per 4-dim group g: [ec[4g..] | em[4g..]]
constexpr size_t OFF_WPRET = 40960;    // u16[768*256] n-major
constexpr size_t OFF_W1T   = 434176;   // u16[256*512]
constexpr size_t OFF_W2T   = 696320;   // u16[256*256]
constexpr size_t OFF_CNT   = 827392;   // i32[NN]   per-node bucket counters
constexpr size_t OFF_SRCET = 907392;   // u32[NN*128]  bucketed CSR: src|et<<16
constexpr size_t OFF_UPDB  = 11147392; // u16[NN*256]  aggregated+modulated upd half (bf16)
constexpr size_t OFF_G     = 21387392; // u16[NN*512]  [P1 row(256) | M row(256)] per node
constexpr size_t OFF_P2B   = 41867392; // u16[NN*256]  P2 + taskc (bf16)
constexpr size_t WS_NEED   = 52107392;

constexpr int ROW_BLOCKS = (NN + 63)/64;   // 313 row-blocks; x4 n-chunks

__device__ __forceinline__ float bf2f(unsigned short u){
  union { unsigned int i; float f; } v; v.i = ((unsigned int)u) << 16; return v.f;
}
__device__ __forceinline__ unsigned short f2bf(float f){
  __bf16 h = (__bf16)f; unsigned short u; __builtin_memcpy(&u, &h, 2); return u;
}
__device__ __forceinline__ float gelu_f(float x){
  return 0.5f * x * (1.0f + erff(x * 0.70710678118654752f));
}
// fast sigmoid-gelu: max abs err ~0.01 vs exact
__device__ __forceinline__ float gelu_fast(float x){
  return x / (1.0f + __expf(-1.702f * x));
}
// overflow-safe fast tanh
__device__ __forceinline__ float tanh_fast(float x){
  float e = __expf(2.0f * x);
  return 1.0f - 2.0f / (e + 1.0f);
}
__device__ __forceinline__ float sum16(const float* p){
  float a = ((p[0]+p[1])+(p[2]+p[3])) + ((p[4]+p[5])+(p[6]+p[7]));
  float b = ((p[8]+p[9])+(p[10]+p[11])) + ((p[12]+p[13])+(p[14]+p[15]));
  return a + b;
}

// ---------------- K_setup: tables + weight transposes + bucketed CSR build ----------------
// blocks [0,35): tables; [35,1315): prep; [1315,2097): CSR (atomic slot + scatter).
// All three groups are mutually independent -> CSR latency hides under table/prep.
__global__ __launch_bounds__(256) void k_setup(
    const float* __restrict__ task, const float* __restrict__ eemb,
    const float* __restrict__ msg_W, const float* __restrict__ msg_b,
    const float* __restrict__ att_W1, const float* __restrict__ att_b1,
    const float* __restrict__ ma_W1, const float* __restrict__ ma_b1,
    const float* __restrict__ ma_W2, const float* __restrict__ ma_b2,
    const float* __restrict__ ua_W1, const float* __restrict__ ua_b1,
    const float* __restrict__ ua_W2, const float* __restrict__ ua_b2,
    const float* __restrict__ up_W1, const float* __restrict__ up_W2,
    const int* __restrict__ eidx, const int* __restrict__ etype,
    float* __restrict__ tabs,
    unsigned short* __restrict__ WpreT, unsigned short* __restrict__ W1T,
    unsigned short* __restrict__ W2T, int* __restrict__ cnt,
    unsigned int* __restrict__ srcet)
{
  __shared__ float s_in[512];
  __shared__ float s_h[512];
  int bb = blockIdx.x, tid = threadIdx.x;
  if (bb >= 1315){
    int e = (bb - 1315)*256 + tid;
    if (e < NE){
      int dst = eidx[NE + e];
      int pos = atomicAdd(&cnt[dst], 1);
      srcet[((unsigned)dst << 7) + pos] =
          (unsigned int)eidx[e] | ((unsigned int)etype[e] << 16);
    }
    return;
  }
  if (bb >= 35){
    int b = bb - 35;
    if (b < 768){
      int n = b;
      float v;
      if (n < 256)      v = msg_W[tid*256 + n];
      else if (n < 512) v = att_W1[tid*256 + (n - 256)];
      else              v = att_W1[(256 + tid)*256 + (n - 512)];
      WpreT[n*256 + tid] = f2bf(v);
    } else if (b < 1024){
      int n = b - 768;
      W1T[n*512 + tid]       = f2bf(up_W1[tid*256 + n]);
      W1T[n*512 + 256 + tid] = f2bf(up_W1[(256 + tid)*256 + n]);
    } else {
      int n = b - 1024;
      W2T[n*256 + tid] = f2bf(up_W2[tid*256 + n]);
    }
    return;
  }
  int b = bb;
  if (b < 2){
    const float* W1 = b ? ua_W1 : ma_W1;  const float* b1 = b ? ua_b1 : ma_b1;
    const float* W2 = b ? ua_W2 : ma_W2;  const float* b2 = b ? ua_b2 : ma_b2;
    s_in[tid] = task[tid];
    __syncthreads();
    #pragma unroll
    for (int jj = 0; jj < 2; ++jj){
      int j = tid + jj*256;
      float pacc[16];
      #pragma unroll
      for (int u = 0; u < 16; ++u) pacc[u] = 0.f;
      for (int k0 = 0; k0 < 256; k0 += 16){
        float wv[16];
        #pragma unroll
        for (int u = 0; u < 16; ++u) wv[u] = W1[(k0 + u)*512 + j];
        #pragma unroll
        for (int u = 0; u < 16; ++u) pacc[u] += s_in[k0 + u] * wv[u];
      }
      s_h[j] = gelu_f(b1[j] + sum16(pacc));
    }
    __syncthreads();
    float o[2];
    #pragma unroll
    for (int jj = 0; jj < 2; ++jj){
      int j = tid + jj*256;
      float pacc[16];
      #pragma unroll
      for (int u = 0; u < 16; ++u) pacc[u] = 0.f;
      for (int k0 = 0; k0 < 512; k0 += 16){
        float wv[16];
        #pragma unroll
        for (int u = 0; u < 16; ++u) wv[u] = W2[(k0 + u)*512 + j];
        #pragma unroll
        for (int u = 0; u < 16; ++u) pacc[u] += s_h[k0 + u] * wv[u];
      }
      o[jj] = b2[j] + sum16(pacc);
    }
    float* scale = tabs + (b ? TAB_UPD_SCALE : TAB_MSG_SCALE);
    float* beta  = tabs + (b ? TAB_UPD_BETA  : TAB_MSG_BETA);
    scale[tid] = 1.0f + 0.5f * tanhf(o[0]);
    beta[tid]  = o[1];
  } else if (b == 2){
    s_in[tid] = task[tid];
    __syncthreads();
    float pacc[16];
    #pragma unroll
    for (int u = 0; u < 16; ++u) pacc[u] = 0.f;
    for (int k0 = 0; k0 < 256; k0 += 16){
      float wv[16];
      #pragma unroll
      for (int u = 0; u < 16; ++u) wv[u] = att_W1[(768 + k0 + u)*256 + tid];
      #pragma unroll
      for (int u = 0; u < 16; ++u) pacc[u] += s_in[k0 + u] * wv[u];
    }
    tabs[TAB_TASKC + tid] = att_b1[tid] + sum16(pacc);
  } else if (b < 19){
    // EM (message table): ECM group-interleaved, +4 half
    int t = b - 3;
    s_in[tid] = eemb[t*256 + tid];
    __syncthreads();
    float pacc[16];
    #pragma unroll
    for (int u = 0; u < 16; ++u) pacc[u] = 0.f;
    for (int k0 = 0; k0 < 256; k0 += 16){
      float wv[16];
      #pragma unroll
      for (int u = 0; u < 16; ++u) wv[u] = msg_W[(k0 + u)*256 + tid];
      #pragma unroll
      for (int u = 0; u < 16; ++u) pacc[u] += s_in[k0 + u] * wv[u];
    }
    tabs[TAB_ECM + t*512 + ((tid >> 2) << 3) + 4 + (tid & 3)] = msg_b[tid] + sum16(pacc);
  } else {
    // EC (attention table): ECM group-interleaved, base half
    int t = b - 19;
    s_in[tid] = eemb[t*256 + tid];
    __syncthreads();
    float pacc[16];
    #pragma unroll
    for (int u = 0; u < 16; ++u) pacc[u] = 0.f;
    for (int k0 = 0; k0 < 256; k0 += 16){
      float wv[16];
      #pragma unroll
      for (int u = 0; u < 16; ++u) wv[u] = att_W1[(512 + k0 + u)*256 + tid];
      #pragma unroll
      for (int u = 0; u < 16; ++u) pacc[u] += s_in[k0 + u] * wv[u];
    }
    tabs[TAB_ECM + t*512 + ((tid >> 2) << 3) + (tid & 3)] = sum16(pacc);
  }
}

// ---------------- K1: LDS-staged B, 2D grid (313 row-blocks x 4 n-chunks) ----------------
__global__ __launch_bounds__(256) void k_gemm_pre(
    const float* __restrict__ X, const unsigned short* __restrict__ WpreT,
    const float* __restrict__ tabs,
    unsigned short* __restrict__ G, unsigned short* __restrict__ P2b)
{
  __shared__ __align__(16) unsigned short s_b[16*256]; // 8KB, swizzled elem ^= (n&7)<<3
  int tid = threadIdx.x;
  int bb = blockIdx.x;
  int rb = bb >> 2, chunk = bb & 3;
  int wv = tid >> 6, lane = tid & 63;
  int m0 = rb*64 + wv*16;
  bool valid = (m0 < NN);
  int lo = lane & 15, hi = lane >> 4;
  bf16x8 a[8];
  if (valid){
    const float* xrow = X + (size_t)(m0 + lo)*256 + hi*8;
    #pragma unroll
    for (int kc = 0; kc < 8; ++kc){
      float4 f0 = *(const float4*)(xrow + kc*32);
      float4 f1 = *(const float4*)(xrow + kc*32 + 4);
      bf16x8 v;
      v[0]=(__bf16)f0.x; v[1]=(__bf16)f0.y; v[2]=(__bf16)f0.z; v[3]=(__bf16)f0.w;
      v[4]=(__bf16)f1.x; v[5]=(__bf16)f1.y; v[6]=(__bf16)f1.z; v[7]=(__bf16)f1.w;
      a[kc] = v;
    }
  }
  int sn = tid >> 4, sk0 = (tid & 15)*16;
  int sswz = (sn & 7) << 3;
  int rswz = (lo & 7) << 3;
  for (int t = 0; t < 12; ++t){
    int nt = chunk*12 + t;
    __syncthreads();
    {
      const unsigned short* gsrc = WpreT + (size_t)(nt*16 + sn)*256 + sk0;
      uint4 d0 = *(const uint4*)(gsrc);
      uint4 d1 = *(const uint4*)(gsrc + 8);
      *(uint4*)(s_b + sn*256 + (sk0 ^ sswz))       = d0;
      *(uint4*)(s_b + sn*256 + ((sk0 + 8) ^ sswz)) = d1;
    }
    __syncthreads();
    if (!valid) continue;
    f32x4 acc = {0.f, 0.f, 0.f, 0.f};
    #pragma unroll
    for (int kc = 0; kc < 8; ++kc){
      bf16x8 bfrag = *(const bf16x8*)(s_b + lo*256 + ((kc*32 + hi*8) ^ rswz));
      acc = __builtin_amdgcn_mfma_f32_16x16x32_bf16(a[kc], bfrag, acc, 0, 0, 0);
    }
    int n0 = nt*16;
    if (nt < 16){
      int j = n0 + lo;
      unsigned short* grow = G + (size_t)(m0 + hi*4)*512 + 256 + j;
      #pragma unroll
      for (int r = 0; r < 4; ++r) grow[(size_t)r*512] = f2bf(acc[r]);
    } else if (nt < 32){
      int j = n0 - 256 + lo;
      unsigned short* grow = G + (size_t)(m0 + hi*4)*512 + j;
      #pragma unroll
      for (int r = 0; r < 4; ++r) grow[(size_t)r*512] = f2bf(acc[r]);
    } else {
      int j = n0 - 512 + lo;
      float tcadd = tabs[TAB_TASKC + j];
      unsigned short* prow = P2b + (size_t)(m0 + hi*4)*256 + j;
      #pragma unroll
      for (int r = 0; r < 4; ++r) prow[(size_t)r*256] = f2bf(acc[r] + tcadd);
    }
  }
}

// ---------------- K3: 2 nodes/wave (proven round-15 structure; bucketed CSR) ----------------
__global__ __launch_bounds__(256) void k_agg(
    const int* __restrict__ cnt, const unsigned int* __restrict__ srcet,
    const unsigned short* __restrict__ G, const unsigned short* __restrict__ P2b,
    const float* __restrict__ tabs, const float* __restrict__ attW2,
    const float* __restrict__ attb2, const float* __restrict__ escale,
    unsigned short* __restrict__ updB)
{
  int wv = threadIdx.x >> 6, lane = threadIdx.x & 63;
  int h = lane >> 5, l = lane & 31;
  int node = blockIdx.x*8 + wv*2 + h;     // grid 2500*8 = NN exactly
  int d0 = l*8;
  float sc = escale[0], bb = attb2[0];

  float q[8], w2v[8];
  {
    u16x8 p2 = *(const u16x8*)(P2b + (size_t)node*256 + d0);
    #pragma unroll
    for (int j = 0; j < 8; ++j) q[j] = bf2f(p2[j]);
    float4 wa = *(const float4*)(attW2 + d0);
    float4 wb = *(const float4*)(attW2 + d0 + 4);
    w2v[0]=wa.x; w2v[1]=wa.y; w2v[2]=wa.z; w2v[3]=wa.w;
    w2v[4]=wb.x; w2v[5]=wb.y; w2v[6]=wb.z; w2v[7]=wb.w;
  }
  const float* ecm_base = tabs + TAB_ECM + (l << 4);   // lane covers groups 2l,2l+1

  int start = node << 7;
  int end = start + cnt[node];
  float acc[8];
  #pragma unroll
  for (int j = 0; j < 8; ++j) acc[j] = 0.f;
  float W = 0.f;

  unsigned int se0 = 0, se1 = 0;
  u16x8 p1a = {0,0,0,0,0,0,0,0}, mma = {0,0,0,0,0,0,0,0};
  if (start < end){
    se0 = srcet[start];
    const unsigned short* gr = G + (((unsigned)(se0 & 0xFFFFu)) << 9);
    p1a = *(const u16x8*)(gr + d0);
    mma = *(const u16x8*)(gr + 256 + d0);
    if (start + 1 < end) se1 = srcet[start + 1];
  }
  for (int i = start; i < end; ++i){
    u16x8 p1b = p1a, mmb = mma;
    unsigned int se2 = 0;
    if (i + 1 < end){
      const unsigned short* gr = G + (((unsigned)(se1 & 0xFFFFu)) << 9);
      p1b = *(const u16x8*)(gr + d0);
      mmb = *(const u16x8*)(gr + 256 + d0);
    }
    if (i + 2 < end) se2 = srcet[i + 2];
    int et = (int)(se0 >> 16);
    const float* ecm = ecm_base + (et << 9);
    float4 ec0 = *(const float4*)(ecm);
    float4 em0 = *(const float4*)(ecm + 4);
    float4 ec1 = *(const float4*)(ecm + 8);
    float4 em1 = *(const float4*)(ecm + 12);
    float part =
        gelu_fast(bf2f(p1a[0]) + q[0] + ec0.x)*w2v[0]
      + gelu_fast(bf2f(p1a[1]) + q[1] + ec0.y)*w2v[1]
      + gelu_fast(bf2f(p1a[2]) + q[2] + ec0.z)*w2v[2]
      + gelu_fast(bf2f(p1a[3]) + q[3] + ec0.w)*w2v[3]
      + gelu_fast(bf2f(p1a[4]) + q[4] + ec1.x)*w2v[4]
      + gelu_fast(bf2f(p1a[5]) + q[5] + ec1.y)*w2v[5]
      + gelu_fast(bf2f(p1a[6]) + q[6] + ec1.z)*w2v[6]
      + gelu_fast(bf2f(p1a[7]) + q[7] + ec1.w)*w2v[7];
    // reduce within 32-lane half (offsets < 32 never cross the h split)
    part += __shfl_xor(part, 1);
    part += __shfl_xor(part, 2);
    part += __shfl_xor(part, 4);
    part += __shfl_xor(part, 8);
    part += __shfl_xor(part, 16);
    float w = 1.0f + sc*tanh_fast(part + bb);
    acc[0] += w*(bf2f(mma[0]) + em0.x);
    acc[1] += w*(bf2f(mma[1]) + em0.y);
    acc[2] += w*(bf2f(mma[2]) + em0.z);
    acc[3] += w*(bf2f(mma[3]) + em0.w);
    acc[4] += w*(bf2f(mma[4]) + em1.x);
    acc[5] += w*(bf2f(mma[5]) + em1.y);
    acc[6] += w*(bf2f(mma[6]) + em1.z);
    acc[7] += w*(bf2f(mma[7]) + em1.w);
    W += w;
    se0 = se1; se1 = se2; p1a = p1b; mma = mmb;
  }

  float d = fmaxf(W, 1.0f), rd = 1.0f / d;
  unsigned short st[8];
  #pragma unroll
  for (int c = 0; c < 2; ++c){
    float4 ms = *(const float4*)(tabs + TAB_MSG_SCALE + d0 + c*4);
    float4 mb = *(const float4*)(tabs + TAB_MSG_BETA  + d0 + c*4);
    float4 us = *(const float4*)(tabs + TAB_UPD_SCALE + d0 + c*4);
    float4 ub = *(const float4*)(tabs + TAB_UPD_BETA  + d0 + c*4);
    st[c*4+0] = f2bf((ms.x*acc[c*4+0] + mb.x*W)*rd*us.x + ub.x);
    st[c*4+1] = f2bf((ms.y*acc[c*4+1] + mb.y*W)*rd*us.y + ub.y);
    st[c*4+2] = f2bf((ms.z*acc[c*4+2] + mb.z*W)*rd*us.z + ub.z);
    st[c*4+3] = f2bf((ms.w*acc[c*4+3] + mb.w*W)*rd*us.w + ub.w);
  }
  *(u16x8*)(updB + (size_t)node*256 + d0) = *(u16x8*)(st);
}

// ---------------- K4: 32-row dense MLP + residual + in-register LayerNorm (proven) ----------------
__device__ __forceinline__ bf16x8 ldA(const float* xrow, const unsigned short* urow, int ke){
  if (ke < 256){
    float4 f0 = *(const float4*)(xrow + ke);
    float4 f1 = *(const float4*)(xrow + ke + 4);
    bf16x8 v;
    v[0]=(__bf16)f0.x; v[1]=(__bf16)f0.y; v[2]=(__bf16)f0.z; v[3]=(__bf16)f0.w;
    v[4]=(__bf16)f1.x; v[5]=(__bf16)f1.y; v[6]=(__bf16)f1.z; v[7]=(__bf16)f1.w;
    return v;
  }
  return *(const bf16x8*)(urow + (ke - 256));
}

__global__ __launch_bounds__(256) void k_mlp(
    const float* __restrict__ X, const unsigned short* __restrict__ updB,
    const unsigned short* __restrict__ W1T, const unsigned short* __restrict__ W2T,
    const float* __restrict__ up_b1, const float* __restrict__ up_b2,
    const float* __restrict__ ln_g, const float* __restrict__ ln_b,
    float* __restrict__ out)
{
  __shared__ __align__(16) unsigned short s_H[32*256]; // bf16, ^=(row&7)<<3
  __shared__ float s_sum[4*32], s_sq[4*32];
  __shared__ float s_mu[32], s_rs[32];
  int m0 = blockIdx.x*32;
  int tid = threadIdx.x;
  int wv = tid >> 6, lane = tid & 63, lo = lane & 15, hi = lane >> 4;

  const float* x0 = X + (size_t)(m0 + lo)*256;
  const float* x1 = x0 + 16*256;
  const unsigned short* u0 = updB + (size_t)(m0 + lo)*256;
  const unsigned short* u1 = u0 + 16*256;

  f32x4 acc0[4], acc1[4];
  #pragma unroll
  for (int t = 0; t < 4; ++t){
    float b = up_b1[wv*64 + t*16 + lo];
    acc0[t] = (f32x4){b, b, b, b};
    acc1[t] = acc0[t];
  }
  #pragma unroll
  for (int kc = 0; kc < 16; ++kc){
    int ke = kc*32 + hi*8;
    bf16x8 a0 = ldA(x0, u0, ke);
    bf16x8 a1 = ldA(x1, u1, ke);
    #pragma unroll
    for (int t = 0; t < 4; ++t){
      int n = wv*64 + t*16 + lo;
      bf16x8 bf = *(const bf16x8*)(W1T + (size_t)n*512 + ke);
      acc0[t] = __builtin_amdgcn_mfma_f32_16x16x32_bf16(a0, bf, acc0[t], 0, 0, 0);
      acc1[t] = __builtin_amdgcn_mfma_f32_16x16x32_bf16(a1, bf, acc1[t], 0, 0, 0);
    }
  }
  #pragma unroll
  for (int t = 0; t < 4; ++t){
    #pragma unroll
    for (int r = 0; r < 4; ++r){
      int row0 = hi*4 + r, n = wv*64 + t*16 + lo;
      s_H[(row0 << 8) | (n ^ ((row0 & 7) << 3))] = f2bf(gelu_fast(acc0[t][r]));
      int row1 = row0 + 16;
      s_H[(row1 << 8) | (n ^ ((row1 & 7) << 3))] = f2bf(gelu_fast(acc1[t][r]));
    }
  }
  __syncthreads();

  f32x4 y0[4], y1[4];
  #pragma unroll
  for (int t = 0; t < 4; ++t){
    float b = up_b2[wv*64 + t*16 + lo];
    y0[t] = (f32x4){b, b, b, b};
    y1[t] = y0[t];
  }
  #pragma unroll
  for (int kc = 0; kc < 8; ++kc){
    int ke = kc*32 + hi*8;
    bf16x8 af0 = *(const bf16x8*)(s_H + ((lo << 8) | (ke ^ ((lo & 7) << 3))));
    int r1 = lo + 16;
    bf16x8 af1 = *(const bf16x8*)(s_H + ((r1 << 8) | (ke ^ ((r1 & 7) << 3))));
    #pragma unroll
    for (int t = 0; t < 4; ++t){
      int n = wv*64 + t*16 + lo;
      bf16x8 bf = *(const bf16x8*)(W2T + (size_t)n*256 + ke);
      y0[t] = __builtin_amdgcn_mfma_f32_16x16x32_bf16(af0, bf, y0[t], 0, 0, 0);
      y1[t] = __builtin_amdgcn_mfma_f32_16x16x32_bf16(af1, bf, y1[t], 0, 0, 0);
    }
  }

  #pragma unroll
  for (int t = 0; t < 4; ++t){
    #pragma unroll
    for (int r = 0; r < 4; ++r){
      int row0 = hi*4 + r, n = wv*64 + t*16 + lo;
      y0[t][r] += X[(size_t)(m0 + row0)*256 + n];
      y1[t][r] += X[(size_t)(m0 + row0 + 16)*256 + n];
    }
  }

  float ps[2][4], pq[2][4];
  #pragma unroll
  for (int r = 0; r < 4; ++r){
    float s0 = 0.f, q0 = 0.f, s1 = 0.f, q1 = 0.f;
    #pragma unroll
    for (int t = 0; t < 4; ++t){
      s0 += y0[t][r]; q0 += y0[t][r]*y0[t][r];
      s1 += y1[t][r]; q1 += y1[t][r]*y1[t][r];
    }
    #pragma unroll
    for (int off = 1; off < 16; off <<= 1){
      s0 += __shfl_xor(s0, off); q0 += __shfl_xor(q0, off);
      s1 += __shfl_xor(s1, off); q1 += __shfl_xor(q1, off);
    }
    ps[0][r] = s0; pq[0][r] = q0;
    ps[1][r] = s1; pq[1][r] = q1;
  }
  if (lo == 0){
    #pragma unroll
    for (int m = 0; m < 2; ++m){
      #pragma unroll
      for (int r = 0; r < 4; ++r){
        int row = m*16 + hi*4 + r;
        s_sum[wv*32 + row] = ps[m][r];
        s_sq [wv*32 + row] = pq[m][r];
      }
    }
  }
  __syncthreads();
  if (tid < 32){
    float sum = s_sum[tid] + s_sum[32 + tid] + s_sum[64 + tid] + s_sum[96 + tid];
    float sq  = s_sq[tid]  + s_sq[32 + tid]  + s_sq[64 + tid]  + s_sq[96 + tid];
    float mu = sum * (1.0f/256.0f);
    float var = sq * (1.0f/256.0f) - mu*mu;
    s_mu[tid] = mu;
    s_rs[tid] = rsqrtf(var + 1e-5f);
  }
  __syncthreads();

  #pragma unroll
  for (int t = 0; t < 4; ++t){
    int n = wv*64 + t*16 + lo;
    float lg = ln_g[n], lb = ln_b[n];
    #pragma unroll
    for (int r = 0; r < 4; ++r){
      int row0 = hi*4 + r, row1 = row0 + 16;
      out[(size_t)(m0 + row0)*256 + n] = (y0[t][r] - s_mu[row0]) * s_rs[row0] * lg + lb;
      out[(size_t)(m0 + row1)*256 + n] = (y1[t][r] - s_mu[row1]) * s_rs[row1] * lg + lb;
    }
  }
}

extern "C" void kernel_launch(void* const* d_in, const int* in_sizes, int n_in,
                              void* d_out, int out_size, void* d_ws, size_t ws_size,
                              hipStream_t stream)
{
  (void)in_sizes; (void)n_in; (void)out_size;
  if (ws_size < WS_NEED) return;
  const float* X      = (const float*)d_in[0];
  const int*   eidx   = (const int*)d_in[1];
  const int*   etype  = (const int*)d_in[2];
  const float* task   = (const float*)d_in[3];
  const float* eemb   = (const float*)d_in[4];
  const float* msg_W  = (const float*)d_in[5];
  const float* msg_b  = (const float*)d_in[6];
  const float* att_W1 = (const float*)d_in[7];
  const float* att_b1 = (const float*)d_in[8];
  const float* att_W2 = (const float*)d_in[9];
  const float* att_b2 = (const float*)d_in[10];
  const float* escale = (const float*)d_in[11];
  const float* ma_W1  = (const float*)d_in[12];
  const float* ma_b1  = (const float*)d_in[13];
  const float* ma_W2  = (const float*)d_in[14];
  const float* ma_b2  = (const float*)d_in[15];
  const float* up_W1  = (const float*)d_in[16];
  const float* up_b1  = (const float*)d_in[17];
  const float* up_W2  = (const float*)d_in[18];
  const float* up_b2  = (const float*)d_in[19];
  const float* ua_W1  = (const float*)d_in[20];
  const float* ua_b1  = (const float*)d_in[21];
  const float* ua_W2  = (const float*)d_in[22];
  const float* ua_b2  = (const float*)d_in[23];
  const float* ln_g   = (const float*)d_in[24];
  const float* ln_b   = (const float*)d_in[25];
  char* ws = (char*)d_ws;
  float* tabs = (float*)ws;
  unsigned short* WpreT = (unsigned short*)(ws + OFF_WPRET);
  unsigned short* W1T   = (unsigned short*)(ws + OFF_W1T);
  unsigned short* W2T   = (unsigned short*)(ws + OFF_W2T);
  int*          cnt   = (int*)(ws + OFF_CNT);
  unsigned int* srcet = (unsigned int*)(ws + OFF_SRCET);
  unsigned short* updB = (unsigned short*)(ws + OFF_UPDB);
  unsigned short* G    = (unsigned short*)(ws + OFF_G);
  unsigned short* P2b  = (unsigned short*)(ws + OFF_P2B);
  float* out = (float*)d_out;

  hipMemsetAsync(cnt, 0, (size_t)NN*4, stream);
  k_setup<<<2097, 256, 0, stream>>>(task, eemb, msg_W, msg_b, att_W1, att_b1,
                                    ma_W1, ma_b1, ma_W2, ma_b2,
                                    ua_W1, ua_b1, ua_W2, ua_b2,
                                    up_W1, up_W2, eidx, etype,
                                    tabs, WpreT, W1T, W2T, cnt, srcet);
  k_gemm_pre<<<ROW_BLOCKS*4, 256, 0, stream>>>(X, WpreT, tabs, G, P2b);
  k_agg<<<NN/8, 256, 0, stream>>>(cnt, srcet, G, P2b, tabs,
                                  att_W2, att_b2, escale, updB);
  k_mlp<<<NN/32, 256, 0, stream>>>(X, updB, W1T, W2T, up_b1, up_b2,
                                   ln_g, ln_b, out);
}